// Round 5
// baseline (318.603 us; speedup 1.0000x reference)
//
#include <hip/hip_runtime.h>
#include <stdint.h>

#define NSUP 1024
#define NQRY 32768
#define DIM  64
#define NCLS 64

typedef float  f32x4  __attribute__((ext_vector_type(4)));
typedef short  s16x8  __attribute__((ext_vector_type(8)));
typedef __bf16 bf16x8 __attribute__((ext_vector_type(8)));

static __device__ __forceinline__ unsigned short f2bf(float f) {
  unsigned u = __float_as_uint(f);
  u += 0x7FFFu + ((u >> 16) & 1u);           // round-to-nearest-even
  return (unsigned short)(u >> 16);
}
// broadcast lane `l`'s value of v to all lanes (l may be runtime wave-uniform)
static __device__ __forceinline__ float rl(float v, int l) {
  return __uint_as_float(__builtin_amdgcn_readlane(__float_as_uint(v), l));
}
static __device__ __forceinline__ float rcp_nr(float x) {
  float r = __builtin_amdgcn_rcpf(x);
  return r * fmaf(-x, r, 2.0f);              // 1 Newton step -> ~0.5 ulp
}
static __device__ __forceinline__ float rsq_nr(float x) {
  float r = __builtin_amdgcn_rsqf(x);
  return r * fmaf(-0.5f * x * r, r, 1.5f);
}

// ---------------- Kernel 1: normalize queries -> bf16, + Mid2 block ----------
// blocks [0,2048): prep 16 query rows each. block 2048: Mid2 = tril(S)tril(S)^T + kap*m m^T
__global__ __launch_bounds__(256) void prep_and_mid(
    const float* __restrict__ Xq, const float* __restrict__ mg,
    const float* __restrict__ Sg, const float* __restrict__ kapg,
    unsigned short* __restrict__ Ybf, float* __restrict__ Mid2) {
  __shared__ float Sls[64 * 65];
  __shared__ float mls[64];
  int tid = threadIdx.x;

  if (blockIdx.x < 2048) {
    int lane = tid & 63;
    int wave = tid >> 6;
    int row  = blockIdx.x * 16 + wave * 4 + (lane >> 4);
    int cb   = (lane & 15) * 4;
    float4 v = *(const float4*)(Xq + (size_t)row * 64 + cb);
    float ss = v.x * v.x + v.y * v.y + v.z * v.z + v.w * v.w;
    ss += __shfl_xor(ss, 1);
    ss += __shfl_xor(ss, 2);
    ss += __shfl_xor(ss, 4);
    ss += __shfl_xor(ss, 8);
    float inv = rcp_nr(fmaxf(__builtin_amdgcn_sqrtf(ss), 1e-12f));
    unsigned short a = f2bf(v.x * inv), b = f2bf(v.y * inv);
    unsigned short c = f2bf(v.z * inv), d = f2bf(v.w * inv);
    uint2 o;
    o.x = (unsigned)a | ((unsigned)b << 16);
    o.y = (unsigned)c | ((unsigned)d << 16);
    *(uint2*)(Ybf + (size_t)row * 64 + cb) = o;
    return;
  }

  // Mid2 block
  for (int i = tid; i < 4096; i += 256) Sls[(i >> 6) * 65 + (i & 63)] = Sg[i];
  if (tid < 64) mls[tid] = mg[tid];
  __syncthreads();
  float kap = kapg[0];
  int r_ = tid & 63, cblk = tid >> 6, c0 = cblk * 16;
#pragma unroll 1
  for (int i = 0; i < 16; ++i) {
    int cc = c0 + i;
    int kmax = min(r_, cc);
    float mid = 0.f;
    for (int k = 0; k <= kmax; ++k) mid += Sls[r_ * 65 + k] * Sls[cc * 65 + k];
    Mid2[r_ * 64 + cc] = mid + kap * mls[r_] * mls[cc];
  }
}

// ---------------- Kernel 2: fit — 1 wave per class, ZERO barriers in hot path
// lane r owns row r of the 64x64 matrix in VGPRs. Pivot broadcast = v_readlane.
__global__ __launch_bounds__(64) void fit_classes(
    const float* __restrict__ Xs, const int* __restrict__ ys,
    const float* __restrict__ mg, const float* __restrict__ Mid2,
    const float* __restrict__ nug, const float* __restrict__ kapg,
    unsigned short* __restrict__ LtG, float* __restrict__ Bg) {
  __shared__ int   lst[NSUP];
  __shared__ float Lls[64 * 68];

  int r = threadIdx.x;   // lane
  int j = blockIdx.x;    // class

  // ---- match list (ballot-ranked, fully parallel) + counts ----
  int cnt = 0, n0 = 0;
  for (int b = 0; b < NSUP; b += 64) {
    int yv = ys[b + r];
    unsigned long long mj = __ballot(yv == j);
    unsigned long long m0 = __ballot(yv == 0);
    n0 += (int)__popcll(m0);
    if (yv == j) {
      int rank = cnt + (int)__popcll(mj & ((1ull << r) - 1ull));
      lst[rank] = b + r;
    }
    cnt += (int)__popcll(mj);
  }
  __syncthreads();

  // ---- acc init = Mid2 row r (middle + kappa m m^T) ----
  float a[64];
  {
    const float* mrow = Mid2 + r * 64;
#pragma unroll
    for (int c4 = 0; c4 < 16; ++c4) {
      float4 v = *(const float4*)(mrow + c4 * 4);
      a[c4 * 4 + 0] = v.x; a[c4 * 4 + 1] = v.y;
      a[c4 * 4 + 2] = v.z; a[c4 * 4 + 3] = v.w;
    }
  }

  // ---- Ssum: outer products of normalized support rows ----
  float sumx = 0.f;
  for (int s = 0; s < cnt; ++s) {
    int n = lst[s];                              // uniform LDS read
    float v = Xs[(size_t)n * 64 + r];            // coalesced
    float ss = v * v;
    ss += __shfl_xor(ss, 1);  ss += __shfl_xor(ss, 2);
    ss += __shfl_xor(ss, 4);  ss += __shfl_xor(ss, 8);
    ss += __shfl_xor(ss, 16); ss += __shfl_xor(ss, 32);
    float inv = rcp_nr(fmaxf(__builtin_amdgcn_sqrtf(ss), 1e-12f));
    float xn = v * inv;
    sumx += xn;
#pragma unroll
    for (int c = 0; c < 64; ++c) a[c] = fmaf(xn, rl(xn, c), a[c]);
  }

  // ---- mu (lane r holds mu[r]) ----
  float kap = kapg[0], nuv = nug[0];
  float Njf = (float)cnt, N0f = (float)n0;
  float rkn0 = rcp_nr(kap + N0f);
  float head = kap * rkn0 * mg[r] + N0f * rkn0;
  float mu = head * (sumx * rcp_nr(Njf));

  // ---- sigma = left * (acc - (kap+Nj) mu mu^T) ----
  {
    float left = rcp_nr(nuv + Njf + (float)DIM + 2.0f);
    float t = (kap + Njf) * mu;
#pragma unroll
    for (int c = 0; c < 64; ++c)
      a[c] = left * fmaf(-t, rl(mu, c), a[c]);
  }

  // ---- Gauss-Jordan inverse (SPD, no pivoting), readlane broadcast ----
  float fr = a[0];                     // lane's element of current pivot column
  for (int p = 0; p < 64; ++p) {
    float dval = rl(fr, p);            // A[p][p]
    float dinv = rcp_nr(dval);
    bool isp = (r == p);
    float frd = fr * dinv;
    float colp_v = isp ? dinv : -frd;  // value for column p (c-independent)
    float fnext = 0.f;
#pragma unroll
    for (int c = 0; c < 64; ++c) {
      float pc = rl(a[c], p);          // A[p][c]
      float q  = pc * dinv;
      float nv;
      if (c == p) {                    // uniform condition
        nv = colp_v;
      } else {
        float tmp = fmaf(-fr, q, a[c]);
        nv = isp ? q : tmp;
      }
      a[c] = nv;
      if (c == p + 1) fnext = nv;      // uniform: extract next pivot column
    }
    fr = fnext;
  }

  // ---- A = 0.7*inv + 0.3*I ----
#pragma unroll
  for (int c = 0; c < 64; ++c) {
    float dd = (c == r) ? 0.3f : 0.f;
    a[c] = fmaf(0.7f, a[c], dd);
  }

  // ---- Cholesky A = L L^T (row-per-lane, readlane broadcast) ----
  float fk = a[0];
  for (int k = 0; k < 64; ++k) {
    float akk = rl(fk, k);
    float rs  = rsq_nr(akk);
    float lrk = (r >= k) ? fk * rs : 0.f;   // L[r][k]; 0 for finished rows
    float fnext = 0.f;
#pragma unroll
    for (int c = 0; c < 64; ++c) {
      float nv;
      if (c == k) nv = lrk;                          // finalize column k
      else        nv = fmaf(-lrk, rl(lrk, c), a[c]); // rl==0 for c<k -> no-op
      a[c] = nv;
      if (c == k + 1) fnext = nv;
    }
    fk = fnext;
  }

  // ---- transpose via LDS; emit L^T bf16 + bias = L^T mu ----
#pragma unroll
  for (int c = 0; c < 64; ++c)
    Lls[r * 68 + c] = (c <= r) ? a[c] : 0.f;
  __syncthreads();

  unsigned short* lrow = LtG + (size_t)j * 4096 + r * 64;
  float bias = 0.f;
#pragma unroll
  for (int u = 0; u < 8; ++u) {
    float v0 = Lls[(u * 8 + 0) * 68 + r];
    float v1 = Lls[(u * 8 + 1) * 68 + r];
    float v2 = Lls[(u * 8 + 2) * 68 + r];
    float v3 = Lls[(u * 8 + 3) * 68 + r];
    float v4 = Lls[(u * 8 + 4) * 68 + r];
    float v5 = Lls[(u * 8 + 5) * 68 + r];
    float v6 = Lls[(u * 8 + 6) * 68 + r];
    float v7 = Lls[(u * 8 + 7) * 68 + r];
    bias = fmaf(v0, rl(mu, u * 8 + 0), bias);
    bias = fmaf(v1, rl(mu, u * 8 + 1), bias);
    bias = fmaf(v2, rl(mu, u * 8 + 2), bias);
    bias = fmaf(v3, rl(mu, u * 8 + 3), bias);
    bias = fmaf(v4, rl(mu, u * 8 + 4), bias);
    bias = fmaf(v5, rl(mu, u * 8 + 5), bias);
    bias = fmaf(v6, rl(mu, u * 8 + 6), bias);
    bias = fmaf(v7, rl(mu, u * 8 + 7), bias);
    uint4 w;
    w.x = (unsigned)f2bf(v0) | ((unsigned)f2bf(v1) << 16);
    w.y = (unsigned)f2bf(v2) | ((unsigned)f2bf(v3) << 16);
    w.z = (unsigned)f2bf(v4) | ((unsigned)f2bf(v5) << 16);
    w.w = (unsigned)f2bf(v6) | ((unsigned)f2bf(v7) << 16);
    *(uint4*)(lrow + u * 8) = w;
  }
  Bg[j * 64 + r] = bias;
}

// ---------------- Kernel 3: predict (MFMA, unroll-1 classes, LDS score stash)
// score[q,j] = -|| L_j^T y_q - L_j^T mu_j ||^2; acc init = -L^T mu (MFMA C-in).
// grid 512 = 128 qtiles(256q) x 4 class-quarters; block 256 = 4 waves x 64 q.
__global__ __launch_bounds__(256) void predict_kernel(
    const unsigned short* __restrict__ Ybf, const unsigned short* __restrict__ Lt,
    const float* __restrict__ Bg, float* __restrict__ out) {
  __shared__ float scl[256 * 17];   // per-thread 16 scores, stride 17 (bank-safe)
  int tid   = threadIdx.x;
  int lane  = tid & 63;
  int wave  = tid >> 6;
  int qt    = blockIdx.x >> 2;
  int cg    = blockIdx.x & 3;
  int cbase = cg * 16;
  int qbase = qt * 256 + wave * 64;
  int c = lane & 15, h = lane >> 4;

  // query fragments (B-operand, col = query)
  s16x8 bfr[4][2];
#pragma unroll
  for (int nt = 0; nt < 4; ++nt) {
    const unsigned short* yrow = Ybf + (size_t)(qbase + nt * 16 + c) * 64;
#pragma unroll
    for (int ks = 0; ks < 2; ++ks)
      bfr[nt][ks] = *(const s16x8*)(yrow + ks * 32 + h * 8);
  }

  const unsigned short* ab    = Lt + (size_t)cbase * 4096 + c * 64 + h * 8;
  const float*          bbase = Bg + (size_t)cbase * 64 + h * 4;
  float*                sbase = &scl[tid * 17];

#pragma unroll 1
  for (int jj = 0; jj < 16; ++jj) {
    // L^T fragments: the 6 nonzero (et,ks) blocks of the upper triangle
    const unsigned short* aj = ab + (size_t)jj * 4096;
    s16x8 af0 = *(const s16x8*)(aj + 0);
    s16x8 af1 = *(const s16x8*)(aj + 1024);
    s16x8 af2 = *(const s16x8*)(aj + 32);
    s16x8 af3 = *(const s16x8*)(aj + 1056);
    s16x8 af4 = *(const s16x8*)(aj + 2080);
    s16x8 af5 = *(const s16x8*)(aj + 3104);
    const float* bb = bbase + (size_t)jj * 64;
    float4 b0 = *(const float4*)(bb);
    float4 b1 = *(const float4*)(bb + 16);
    float4 b2 = *(const float4*)(bb + 32);
    float4 b3 = *(const float4*)(bb + 48);
    f32x4 nb0 = {-b0.x, -b0.y, -b0.z, -b0.w};
    f32x4 nb1 = {-b1.x, -b1.y, -b1.z, -b1.w};
    f32x4 nb2 = {-b2.x, -b2.y, -b2.z, -b2.w};
    f32x4 nb3 = {-b3.x, -b3.y, -b3.z, -b3.w};

    float ssel = 0.f;
#pragma unroll
    for (int nt = 0; nt < 4; ++nt) {
      f32x4 a0 = __builtin_amdgcn_mfma_f32_16x16x32_bf16(
          __builtin_bit_cast(bf16x8, af0), __builtin_bit_cast(bf16x8, bfr[nt][0]), nb0, 0, 0, 0);
      a0 = __builtin_amdgcn_mfma_f32_16x16x32_bf16(
          __builtin_bit_cast(bf16x8, af2), __builtin_bit_cast(bf16x8, bfr[nt][1]), a0, 0, 0, 0);
      f32x4 a1 = __builtin_amdgcn_mfma_f32_16x16x32_bf16(
          __builtin_bit_cast(bf16x8, af1), __builtin_bit_cast(bf16x8, bfr[nt][0]), nb1, 0, 0, 0);
      a1 = __builtin_amdgcn_mfma_f32_16x16x32_bf16(
          __builtin_bit_cast(bf16x8, af3), __builtin_bit_cast(bf16x8, bfr[nt][1]), a1, 0, 0, 0);
      f32x4 a2 = __builtin_amdgcn_mfma_f32_16x16x32_bf16(
          __builtin_bit_cast(bf16x8, af4), __builtin_bit_cast(bf16x8, bfr[nt][1]), nb2, 0, 0, 0);
      f32x4 a3 = __builtin_amdgcn_mfma_f32_16x16x32_bf16(
          __builtin_bit_cast(bf16x8, af5), __builtin_bit_cast(bf16x8, bfr[nt][1]), nb3, 0, 0, 0);
      float s = a0[0] * a0[0] + a0[1] * a0[1] + a0[2] * a0[2] + a0[3] * a0[3];
      s += a1[0] * a1[0] + a1[1] * a1[1] + a1[2] * a1[2] + a1[3] * a1[3];
      s += a2[0] * a2[0] + a2[1] * a2[1] + a2[2] * a2[2] + a2[3] * a2[3];
      s += a3[0] * a3[0] + a3[1] * a3[1] + a3[2] * a3[2] + a3[3] * a3[3];
      s += __shfl_xor(s, 16);
      s += __shfl_xor(s, 32);
      if (nt == h) ssel = s;   // lane keeps score for query h*16+c (== lane)
    }
    sbase[jj] = -ssel;
  }

  // readback per-lane scores -> one 64B row segment
  float* orow = out + (size_t)(qbase + lane) * 64 + cbase;
#pragma unroll
  for (int g = 0; g < 4; ++g) {
    f32x4 v = { sbase[g * 4 + 0], sbase[g * 4 + 1],
                sbase[g * 4 + 2], sbase[g * 4 + 3] };
    *(f32x4*)(orow + g * 4) = v;
  }
}

extern "C" void kernel_launch(void* const* d_in, const int* in_sizes, int n_in,
                              void* d_out, int out_size, void* d_ws, size_t ws_size,
                              hipStream_t stream) {
  const float* Xs   = (const float*)d_in[0];
  const int*   ys   = (const int*)d_in[1];
  const float* Xq   = (const float*)d_in[2];
  const float* mg   = (const float*)d_in[3];
  const float* Sg   = (const float*)d_in[4];
  const float* nug  = (const float*)d_in[5];
  const float* kapg = (const float*)d_in[6];
  float* out = (float*)d_out;

  unsigned short* Ybf = (unsigned short*)d_ws;              // NQ*64 bf16 = 4 MB
  unsigned short* LtG = Ybf + (size_t)NQRY * 64;            // 64*4096 bf16 = 512 KB
  float* Bg   = (float*)(LtG + (size_t)NCLS * 4096);        // 64*64 f32
  float* Mid2 = Bg + NCLS * 64;                             // 64*64 f32

  prep_and_mid<<<dim3(2049), dim3(256), 0, stream>>>(Xq, mg, Sg, kapg, Ybf, Mid2);
  fit_classes<<<dim3(NCLS), dim3(64), 0, stream>>>(Xs, ys, mg, Mid2, nug, kapg,
                                                   LtG, Bg);
  predict_kernel<<<dim3(512), dim3(256), 0, stream>>>(Ybf, LtG, Bg, out);
}